// Round 6
// baseline (95.954 us; speedup 1.0000x reference)
//
#include <hip/hip_runtime.h>
#include <math.h>

#define HH 512
#define WW 512
#define NPIX (16*HH*WW)
#define RAD 10
#define KS 21
#define TX 64
#define TY 32
// register-mega tile: 64 wide (incl 2x5 x-halo) x 48 tall (incl 2x5 y-halo)
#define OTX 54
#define OTY 38

__device__ __forceinline__ int refl(int v, int n){ v = v < 0 ? -v : v; return v >= n ? 2*n - 2 - v : v; }
__device__ __forceinline__ float sigm(float x){ return 1.f/(1.f+expf(-x)); }

// P layout: [0]=alpha [1]=lam [2]=beta [3]=xi [4]=eta [5]=nu [6]=gamma [7]=omega
// [8..28]=gauss weights  [30]=saturation flag  [64+32*i]=per-image max slots
__global__ void k_params(const float* a_raw, const float* l_raw, const float* lsig,
                         const float* lbeta, const float* lxi, const float* e_raw,
                         const float* n_raw, const float* lgam, const float* o_raw,
                         float* P)
{
    if (threadIdx.x || blockIdx.x) return;
    float sigma = 0.5f + 4.5f*sigm(lsig[0]);
    float beta  = 1.f + 4.f*sigm(lbeta[0]);
    float xi    = 1.f + 4.f*sigm(lxi[0]);
    float eta   = sigm(e_raw[0]);
    P[0] = 0.6f + 1.4f*sigm(a_raw[0]);
    P[1] = 0.01f + 0.19f*sigm(l_raw[0]);
    P[2] = beta;
    P[3] = xi;
    P[4] = eta;
    P[5] = sigm(n_raw[0]);
    P[6] = 1.f + 3.f*sigm(lgam[0]);
    P[7] = sigm(o_raw[0]);
    float kk[KS], s = 0.f;
    for (int i = 0; i < KS; ++i){ float c = (float)(i-RAD); kk[i] = expf(-c*c/(2.f*sigma*sigma+1e-8f)); s += kk[i]; }
    float inv = 1.f/(s+1e-8f);
    for (int i = 0; i < KS; ++i) P[8+i] = kk[i]*inv;
    // phi saturates at 10 for ALL u in [0,1] iff beta^2*xi >= 100*(eta*g2max+1e-6), g2max=0.5.
    P[30] = (beta*beta*xi >= 100.f*(eta*0.5000002f + 1e-6f)) ? 1.f : 0.f;
    for (int i = 0; i < 16; ++i) P[64+32*i] = 0.f;
}

// Saturated-phi path: all 5 iterations in registers.
// 4 waves; wave w owns tile rows 12w..12w+11 in registers; lane = tile column.
// Band-boundary rows exchanged via tiny double-buffered LDS strip.
__global__ __launch_bounds__(256, 4)
void k_mega(const float* __restrict__ img, const float* __restrict__ lfd,
            float* __restrict__ out_u, const float* __restrict__ P, float* Pmax)
{
    if (P[30] == 0.f) return;
    __shared__ float bnd[2][8][64];
    __shared__ float red[4];
    const int tid  = threadIdx.x;
    const int lane = tid & 63;
    const int w    = tid >> 6;
    const int ox = min((int)blockIdx.x * OTX, WW - OTX);
    const int oy = min((int)blockIdx.y * OTY, HH - OTY);
    const int b  = blockIdx.z;
    const float* ib = img + (b<<18);
    const float* lb = lfd + (b<<18);
    float* ob = out_u + (b<<18);
    const float A = 1e-3f*P[0], lam = P[1], nu = P[5], gam = P[6], omg = P[7];

    const int gxc = refl(ox - 5 + lane, WW);
    const int t0  = 12*w;

    float u[12], u0[12], fw[12];
#pragma unroll
    for (int j = 0; j < 12; ++j){
        int gy = refl(oy - 5 + t0 + j, HH);
        int gi = gy*WW + gxc;
        float v = ib[gi];
        u0[j] = v; u[j] = v;
        fw[j] = fminf(fmaxf(1.f - omg*lb[gi], 0.f), 1.f);
    }
    float fwN0, fwS0;
    { int gy = refl(oy - 6 + t0, HH);  fwN0 = fminf(fmaxf(1.f - omg*lb[gy*WW+gxc], 0.f), 1.f); }
    { int gy = refl(oy + 7 + t0, HH);  fwS0 = fminf(fmaxf(1.f - omg*lb[gy*WW+gxc], 0.f), 1.f); }

#pragma unroll
    for (int K = 1; K <= 5; ++K){
        const int p = K & 1;
        bnd[p][2*w][lane]   = u[0];
        bnd[p][2*w+1][lane] = u[11];
        __syncthreads();
        float uNb = (w > 0) ? bnd[p][2*w-1][lane] : 0.f;
        float uSb = (w < 3) ? bnd[p][2*w+2][lane] : 0.f;
        float um = uNb;                       // old u[j-1]
#pragma unroll
        for (int j = 0; j < 12; ++j){
            const int t = t0 + j;
            float cur = u[j];
            float uS = (j == 11) ? uSb : u[j+1];
            if (t >= K && t <= 47 - K){        // wave-uniform validity
                float uN = um;
                float uE = __shfl_down(cur, 1);
                float uW = __shfl_up(cur, 1);
                float fE = __shfl_down(fw[j], 1);
                float fW = __shfl_up(fw[j], 1);
                float fN = (j == 0)  ? fwN0 : fw[j-1];
                float fS = (j == 11) ? fwS0 : fw[j+1];
                float gyv = (uS - uN)*0.5f, gxv = (uE - uW)*0.5f;
                float lap = (uN + uS) + (uE + uW) - 4.f*cur;
                float g2 = fmaf(gxv, gxv, fmaf(gyv, gyv, 1e-8f));
                float gm = sqrtf(g2);
                float s  = gm*fabsf(lap);
                float psi = sqrtf(fmaf(nu, s*s*s, gam));
                float dv = fN*(uN-cur) + fS*(uS-cur) + fE*(uE-cur) + fW*(uW-cur);
                float du = fmaf(A*psi, dv, -lam*(cur - u0[j]));
                u[j] = fminf(fmaxf(fmaf(0.1f, du, cur), 0.f), 1.f);
            }
            um = cur;
        }
    }

    float mymax = 0.f;
    const bool colv = (lane >= 5) && (lane <= 58);
#pragma unroll
    for (int j = 0; j < 12; ++j){
        const int t = t0 + j;
        if (t >= 5 && t <= 42 && colv){
            int gi = (oy + t - 5)*WW + (ox + lane - 5);
            ob[gi] = u[j];
            mymax = fmaxf(mymax, fabsf(u0[j] - u[j]));
        }
    }
#pragma unroll
    for (int off = 32; off; off >>= 1) mymax = fmaxf(mymax, __shfl_down(mymax, off));
    if (lane == 0) red[w] = mymax;
    __syncthreads();
    if (tid == 0){
        float m = fmaxf(fmaxf(red[0], red[1]), fmaxf(red[2], red[3]));
        atomicMax((unsigned int*)(Pmax + 32*b), __float_as_uint(m));
    }
}

// General-path fallback (fully-fused single iteration). Early-exits when saturated.
__global__ __launch_bounds__(256)
void k_iter(const float* __restrict__ src, const float* __restrict__ img,
            const float* __restrict__ lfd, float* __restrict__ dst,
            const float* __restrict__ P, float* Pmax, int do_max)
{
    if (P[30] != 0.f) return;
    __shared__ __attribute__((aligned(16))) float sh[56][72];
    __shared__ float su[36][72];
    __shared__ float ut[34][72];
    __shared__ float red[4];
    float (*pt)[72] = sh;

    const int tid = threadIdx.x;
    const int x0 = blockIdx.x * TX;
    const int y0 = blockIdx.y * TY;
    const int b  = blockIdx.z;
    const float* sb = src + (b << 18);
    const float* ib = img + (b << 18);
    const float* lb = lfd + (b << 18);
    float* db = dst + (b << 18);

    float kw[KS];
#pragma unroll
    for (int j = 0; j < KS; ++j) kw[j] = P[8 + j];
    const float alpha = P[0], lam = P[1], beta = P[2], xi = P[3];
    const float eta = P[4], nu = P[5], gam = P[6], omg = P[7];

#pragma unroll
    for (int p = 0; p < 9; ++p) {
        int i = tid + p * 256;
        if (i < 34 * 66) {
            int r = i / 66, c = i - r * 66;
            ut[r][c] = sb[refl(y0 - 1 + r, HH) * WW + refl(x0 - 1 + c, WW)];
        }
    }
#pragma unroll
    for (int p = 0; p < 4; ++p) {
        int i = tid + p * 256;
        if (i < 56 * 17) {
            int hr = i / 17, g = i - hr * 17;
            const float* row = sb + refl(y0 - 12 + hr, HH) * WW;
            int gxs = x0 - 12 + 4 * g;
            float wv[24];
            if (gxs >= 0 && gxs + 23 < WW) {
                const float4* p4 = (const float4*)(row + gxs);
#pragma unroll
                for (int q = 0; q < 6; ++q) {
                    float4 v = p4[q];
                    wv[4*q] = v.x; wv[4*q+1] = v.y; wv[4*q+2] = v.z; wv[4*q+3] = v.w;
                }
            } else {
#pragma unroll
                for (int q = 0; q < 24; ++q) wv[q] = row[refl(gxs + q, WW)];
            }
            float a0 = 0.f, a1 = 0.f, a2 = 0.f, a3 = 0.f;
#pragma unroll
            for (int j = 0; j < KS; ++j) {
                a0 = fmaf(kw[j], wv[j],     a0);
                a1 = fmaf(kw[j], wv[j + 1], a1);
                a2 = fmaf(kw[j], wv[j + 2], a2);
                a3 = fmaf(kw[j], wv[j + 3], a3);
            }
            float4 o; o.x = a0; o.y = a1; o.z = a2; o.w = a3;
            *(float4*)&sh[hr][4 * g] = o;
        }
    }
    __syncthreads();
#pragma unroll
    for (int p = 0; p < 3; ++p) {
        int i = tid + p * 256;
        if (i < 9 * 68) {
            int rg = i / 68, c = i - rg * 68;
            int r0 = rg * 4;
            float a0 = 0.f, a1 = 0.f, a2 = 0.f, a3 = 0.f;
#pragma unroll
            for (int q = 0; q < 24; ++q) {
                float s = sh[r0 + q][c];
                if (q <= 20)           a0 = fmaf(kw[q],     s, a0);
                if (q >= 1 && q <= 21) a1 = fmaf(kw[q - 1], s, a1);
                if (q >= 2 && q <= 22) a2 = fmaf(kw[q - 2], s, a2);
                if (q >= 3)            a3 = fmaf(kw[q - 3], s, a3);
            }
            su[r0][c] = a0; su[r0+1][c] = a1; su[r0+2][c] = a2; su[r0+3][c] = a3;
        }
    }
    __syncthreads();
#pragma unroll
    for (int p = 0; p < 9; ++p) {
        int i = tid + p * 256;
        if (i < 34 * 66) {
            int r = i / 66, c = i - r * 66;
            float gys = (su[r + 2][c + 1] - su[r][c + 1]) * 0.5f;
            float gxs = (su[r + 1][c + 2] - su[r + 1][c]) * 0.5f;
            float g2 = fmaf(gxs, gxs, fmaf(gys, gys, 1e-8f));
            float ph = fminf(beta * sqrtf(xi / fmaf(eta, g2, 1e-6f)), 10.f);
            float lv = lb[refl(y0 - 1 + r, HH) * WW + refl(x0 - 1 + c, WW)];
            float fwv = fminf(fmaxf(1.f - omg * lv, 0.f), 1.f);
            pt[r][c] = ph * fwv;
        }
    }
    __syncthreads();
    const int c = tid & 63, r0 = tid >> 6;
    float mymax = 0.f;
#pragma unroll
    for (int p = 0; p < 8; ++p) {
        int r = r0 + p * 4;
        float uc = ut[r + 1][c + 1];
        float uN = ut[r][c + 1],     uS = ut[r + 2][c + 1];
        float uE = ut[r + 1][c + 2], uW = ut[r + 1][c];
        float gy = (uS - uN) * 0.5f, gx = (uE - uW) * 0.5f;
        float lap = uN + uS + uE + uW - 4.f * uc;
        float gm = sqrtf(fmaf(gx, gx, fmaf(gy, gy, 1e-8f)));
        float s = gm * fabsf(lap);
        float psi = 1e-4f * sqrtf(fmaf(nu, s * s * s, gam));
        float pN = pt[r][c + 1],     pS = pt[r + 2][c + 1];
        float pE = pt[r + 1][c + 2], pW = pt[r + 1][c];
        float dv = pN * (uN - uc) + pS * (uS - uc) + pE * (uE - uc) + pW * (uW - uc);
        int gidx = (y0 + r) * WW + x0 + c;
        float u0v = ib[gidx];
        float du = alpha * psi * dv - lam * (uc - u0v);
        float un = fminf(fmaxf(fmaf(0.1f, du, uc), 0.f), 1.f);
        db[gidx] = un;
        mymax = fmaxf(mymax, fabsf(u0v - un));
    }
    if (do_max) {
#pragma unroll
        for (int off = 32; off; off >>= 1) mymax = fmaxf(mymax, __shfl_down(mymax, off));
        if ((tid & 63) == 0) red[tid >> 6] = mymax;
        __syncthreads();
        if (tid == 0) {
            float m = fmaxf(fmaxf(red[0], red[1]), fmaxf(red[2], red[3]));
            atomicMax((unsigned int*)(Pmax + 32 * b), __float_as_uint(m));
        }
    }
}

// residual: r = |img - u| / (max + 1e-8), float4
__global__ void k_res2(const float* __restrict__ img, const float* __restrict__ u,
                       float* __restrict__ r, const float* __restrict__ Pmax)
{
    int i = blockIdx.x * 256 + threadIdx.x;   // float4 index
    int b = i >> 16;
    float inv = 1.f / (Pmax[32 * b] + 1e-8f);
    float4 a = ((const float4*)img)[i];
    float4 c = ((const float4*)u)[i];
    float4 o;
    o.x = fabsf(a.x - c.x) * inv;
    o.y = fabsf(a.y - c.y) * inv;
    o.z = fabsf(a.z - c.z) * inv;
    o.w = fabsf(a.w - c.w) * inv;
    ((float4*)r)[i] = o;
}

extern "C" void kernel_launch(void* const* d_in, const int* in_sizes, int n_in,
                              void* d_out, int out_size, void* d_ws, size_t ws_size,
                              hipStream_t stream)
{
    const float* image = (const float*)d_in[0];
    const float* lfd   = (const float*)d_in[1];

    float* out_u = (float*)d_out;
    float* out_r = out_u + NPIX;

    float* uB = (float*)d_ws;           // NPIX floats (fallback ping-pong)
    float* P  = uB + NPIX;              // params + max slots

    k_params<<<1, 64, 0, stream>>>((const float*)d_in[2], (const float*)d_in[3],
                                   (const float*)d_in[4], (const float*)d_in[5],
                                   (const float*)d_in[6], (const float*)d_in[7],
                                   (const float*)d_in[8], (const float*)d_in[9],
                                   (const float*)d_in[10], P);

    float* Pmax = P + 64;

    // saturated-phi fast path (no-op if not saturated): overlapping 54x38 output tiles
    dim3 grd2((WW + OTX - 1)/OTX, (HH + OTY - 1)/OTY, 16);
    k_mega<<<grd2, 256, 0, stream>>>(image, lfd, out_u, P, Pmax);

    // general fallback (no-op if saturated)
    dim3 grd(WW/TX, HH/TY, 16), blk(256);
    float* bufs[2] = { out_u, uB };
    for (int it = 0; it < 5; ++it) {
        const float* src = (it == 0) ? image : bufs[(it + 1) & 1];
        float* dstp = bufs[it & 1];
        k_iter<<<grd, blk, 0, stream>>>(src, image, lfd, dstp, P, Pmax, it == 4 ? 1 : 0);
    }

    k_res2<<<NPIX/1024, 256, 0, stream>>>(image, out_u, out_r, Pmax);
}

// Round 7
// 91.639 us; speedup vs baseline: 1.0471x; 1.0471x over previous
//
#include <hip/hip_runtime.h>
#include <math.h>

#define HH 512
#define WW 512
#define NPIX (16*HH*WW)
#define RAD 10
#define KS 21
#define TX 64
#define TY 32
// mega: staged 66x66 (LDS stride 76), compute region 64x64, output 56x56
#define MS 66
#define MST 76
#define MO 56

__device__ __forceinline__ int refl(int v, int n){ v = v < 0 ? -v : v; return v >= n ? 2*n - 2 - v : v; }
__device__ __forceinline__ float sigm(float x){ return 1.f/(1.f+expf(-x)); }

// P layout: [0]=alpha [1]=lam [2]=beta [3]=xi [4]=eta [5]=nu [6]=gamma [7]=omega
// [8..28]=gauss weights  [30]=saturation flag  [64+32*i]=per-image max slots
__global__ void k_params(const float* a_raw, const float* l_raw, const float* lsig,
                         const float* lbeta, const float* lxi, const float* e_raw,
                         const float* n_raw, const float* lgam, const float* o_raw,
                         float* P)
{
    if (threadIdx.x || blockIdx.x) return;
    float sigma = 0.5f + 4.5f*sigm(lsig[0]);
    float beta  = 1.f + 4.f*sigm(lbeta[0]);
    float xi    = 1.f + 4.f*sigm(lxi[0]);
    float eta   = sigm(e_raw[0]);
    P[0] = 0.6f + 1.4f*sigm(a_raw[0]);
    P[1] = 0.01f + 0.19f*sigm(l_raw[0]);
    P[2] = beta;
    P[3] = xi;
    P[4] = eta;
    P[5] = sigm(n_raw[0]);
    P[6] = 1.f + 3.f*sigm(lgam[0]);
    P[7] = sigm(o_raw[0]);
    float kk[KS], s = 0.f;
    for (int i = 0; i < KS; ++i){ float c = (float)(i-RAD); kk[i] = expf(-c*c/(2.f*sigma*sigma+1e-8f)); s += kk[i]; }
    float inv = 1.f/(s+1e-8f);
    for (int i = 0; i < KS; ++i) P[8+i] = kk[i]*inv;
    // phi saturates at 10 for ALL u in [0,1] iff beta^2*xi >= 100*(eta*g2max+1e-6), g2max=0.5.
    P[30] = (beta*beta*xi >= 100.f*(eta*0.5000002f + 1e-6f)) ? 1.f : 0.f;
    for (int i = 0; i < 16; ++i) P[64+32*i] = 0.f;
}

// Saturated-phi path: 5 iterations, u in LDS ping-pong, static 4x4 patch per thread.
// Fixed 64x64 compute region every iteration (invalid ring never feeds valid cells).
// fw + u0 held in registers across iterations. Output 56x56 per tile (overlapping,
// overlapped pixels bitwise identical).
__global__ __launch_bounds__(256, 4)
void k_mega(const float* __restrict__ img, const float* __restrict__ lfd,
            float* __restrict__ out_u, const float* __restrict__ P, float* Pmax)
{
    if (P[30] == 0.f) return;
    __shared__ __attribute__((aligned(16))) float SA[MS][MST];
    __shared__ __attribute__((aligned(16))) float SB[MS][MST];
    __shared__ float red[4];
    const int tid = threadIdx.x;
    const int tx = tid & 15, ty = tid >> 4;
    const int ox = min((int)blockIdx.x * MO, WW - MO);
    const int oy = min((int)blockIdx.y * MO, HH - MO);
    const int b = blockIdx.z;
    const float* ib = img + (b<<18);
    const float* lb = lfd + (b<<18);
    float* ob = out_u + (b<<18);
    const float A = 1e-3f*P[0], lam = P[1], nu = P[5], gam = P[6], omg = P[7];
    const bool bord = (ox == 0) | (oy == 0) | (ox > WW - MS + 5) | (oy > HH - MS + 5);

    // stage u0 -> SA, fw -> SB (SB is free until iteration 1 writes it)
    for (int i = tid; i < MS*MS; i += 256){
        int rr = i/MS, cc = i - rr*MS;
        int gy = oy - 5 + rr, gx = ox - 5 + cc;
        if (bord){ gy = refl(gy, HH); gx = refl(gx, WW); }
        int gi = gy*WW + gx;
        SA[rr][cc+3] = ib[gi];
        SB[rr][cc+3] = fminf(fmaxf(1.f - omg*lb[gi], 0.f), 1.f);
    }
    __syncthreads();

    const int r  = 1 + 4*ty;     // logical row of first cell (logical row == phys row)
    const int cp = 4 + 4*tx;     // physical col of first cell (logical col 1+4tx)

    // hoist fw window + u0 patch into registers
    float fNS[6][4]; float fW4[4], fE4[4]; float u0a[4][4];
#pragma unroll
    for (int j = 0; j < 6; ++j) *(float4*)fNS[j] = *(const float4*)&SB[r-1+j][cp];
#pragma unroll
    for (int j = 0; j < 4; ++j){ fW4[j] = SB[r+j][cp-1]; fE4[j] = SB[r+j][cp+4]; }
#pragma unroll
    for (int j = 0; j < 4; ++j) *(float4*)u0a[j] = *(const float4*)&SA[r+j][cp];
    __syncthreads();

    float mymax = 0.f;
    const bool inner = (tx >= 1) & (tx <= 14) & (ty >= 1) & (ty <= 14);
    const int gy0 = oy + r - 5, gx0 = ox + 4*tx - 4;

#define STEP(SRC, DST, LAST) { \
    float uq[6][4]; float uwv[4], uev[4]; \
    _Pragma("unroll") for (int j = 0; j < 6; ++j) *(float4*)uq[j] = *(const float4*)&SRC[r-1+j][cp]; \
    _Pragma("unroll") for (int j = 0; j < 4; ++j){ uwv[j] = SRC[r+j][cp-1]; uev[j] = SRC[r+j][cp+4]; } \
    _Pragma("unroll") for (int j = 0; j < 4; ++j){ \
        float un[4]; \
        _Pragma("unroll") for (int k = 0; k < 4; ++k){ \
            float uc = uq[j+1][k]; \
            float uN = uq[j][k], uS = uq[j+2][k]; \
            float uW = (k==0) ? uwv[j] : uq[j+1][k-1]; \
            float uE = (k==3) ? uev[j] : uq[j+1][k+1]; \
            float fN = fNS[j][k], fS = fNS[j+2][k]; \
            float fWv = (k==0) ? fW4[j] : fNS[j+1][k-1]; \
            float fEv = (k==3) ? fE4[j] : fNS[j+1][k+1]; \
            float gyv = (uS-uN)*0.5f, gxv = (uE-uW)*0.5f; \
            float lap = (uN+uS)+(uE+uW) - 4.f*uc; \
            float gm = sqrtf(fmaf(gxv,gxv, fmaf(gyv,gyv, 1e-8f))); \
            float s = gm*fabsf(lap); \
            float psi = sqrtf(fmaf(nu, s*s*s, gam)); \
            float dv = fN*(uN-uc) + fS*(uS-uc) + fEv*(uE-uc) + fWv*(uW-uc); \
            float du = fmaf(A*psi, dv, -lam*(uc - u0a[j][k])); \
            un[k] = fminf(fmaxf(fmaf(0.1f, du, uc), 0.f), 1.f); \
        } \
        if (LAST){ \
            if (inner){ \
                _Pragma("unroll") for (int k = 0; k < 4; ++k){ \
                    ob[(gy0+j)*WW + gx0 + k] = un[k]; \
                    mymax = fmaxf(mymax, fabsf(u0a[j][k] - un[k])); \
                } \
            } \
        } else { \
            *(float4*)&DST[r+j][cp] = *(float4*)un; \
        } \
    } \
    if (!LAST) __syncthreads(); }

    STEP(SA, SB, 0)
    STEP(SB, SA, 0)
    STEP(SA, SB, 0)
    STEP(SB, SA, 0)
    STEP(SA, SB, 1)
#undef STEP

#pragma unroll
    for (int off = 32; off; off >>= 1) mymax = fmaxf(mymax, __shfl_down(mymax, off));
    if ((tid & 63) == 0) red[tid >> 6] = mymax;
    __syncthreads();
    if (tid == 0){
        float m = fmaxf(fmaxf(red[0], red[1]), fmaxf(red[2], red[3]));
        atomicMax((unsigned int*)(Pmax + 32*b), __float_as_uint(m));
    }
}

// General-path fallback (fully-fused single iteration). Early-exits when saturated.
__global__ __launch_bounds__(256)
void k_iter(const float* __restrict__ src, const float* __restrict__ img,
            const float* __restrict__ lfd, float* __restrict__ dst,
            const float* __restrict__ P, float* Pmax, int do_max)
{
    if (P[30] != 0.f) return;
    __shared__ __attribute__((aligned(16))) float sh[56][72];
    __shared__ float su[36][72];
    __shared__ float ut[34][72];
    __shared__ float red[4];
    float (*pt)[72] = sh;

    const int tid = threadIdx.x;
    const int x0 = blockIdx.x * TX;
    const int y0 = blockIdx.y * TY;
    const int b  = blockIdx.z;
    const float* sb = src + (b << 18);
    const float* ib = img + (b << 18);
    const float* lb = lfd + (b << 18);
    float* db = dst + (b << 18);

    float kw[KS];
#pragma unroll
    for (int j = 0; j < KS; ++j) kw[j] = P[8 + j];
    const float alpha = P[0], lam = P[1], beta = P[2], xi = P[3];
    const float eta = P[4], nu = P[5], gam = P[6], omg = P[7];

#pragma unroll
    for (int p = 0; p < 9; ++p) {
        int i = tid + p * 256;
        if (i < 34 * 66) {
            int r = i / 66, c = i - r * 66;
            ut[r][c] = sb[refl(y0 - 1 + r, HH) * WW + refl(x0 - 1 + c, WW)];
        }
    }
#pragma unroll
    for (int p = 0; p < 4; ++p) {
        int i = tid + p * 256;
        if (i < 56 * 17) {
            int hr = i / 17, g = i - hr * 17;
            const float* row = sb + refl(y0 - 12 + hr, HH) * WW;
            int gxs = x0 - 12 + 4 * g;
            float wv[24];
            if (gxs >= 0 && gxs + 23 < WW) {
                const float4* p4 = (const float4*)(row + gxs);
#pragma unroll
                for (int q = 0; q < 6; ++q) {
                    float4 v = p4[q];
                    wv[4*q] = v.x; wv[4*q+1] = v.y; wv[4*q+2] = v.z; wv[4*q+3] = v.w;
                }
            } else {
#pragma unroll
                for (int q = 0; q < 24; ++q) wv[q] = row[refl(gxs + q, WW)];
            }
            float a0 = 0.f, a1 = 0.f, a2 = 0.f, a3 = 0.f;
#pragma unroll
            for (int j = 0; j < KS; ++j) {
                a0 = fmaf(kw[j], wv[j],     a0);
                a1 = fmaf(kw[j], wv[j + 1], a1);
                a2 = fmaf(kw[j], wv[j + 2], a2);
                a3 = fmaf(kw[j], wv[j + 3], a3);
            }
            float4 o; o.x = a0; o.y = a1; o.z = a2; o.w = a3;
            *(float4*)&sh[hr][4 * g] = o;
        }
    }
    __syncthreads();
#pragma unroll
    for (int p = 0; p < 3; ++p) {
        int i = tid + p * 256;
        if (i < 9 * 68) {
            int rg = i / 68, c = i - rg * 68;
            int r0 = rg * 4;
            float a0 = 0.f, a1 = 0.f, a2 = 0.f, a3 = 0.f;
#pragma unroll
            for (int q = 0; q < 24; ++q) {
                float s = sh[r0 + q][c];
                if (q <= 20)           a0 = fmaf(kw[q],     s, a0);
                if (q >= 1 && q <= 21) a1 = fmaf(kw[q - 1], s, a1);
                if (q >= 2 && q <= 22) a2 = fmaf(kw[q - 2], s, a2);
                if (q >= 3)            a3 = fmaf(kw[q - 3], s, a3);
            }
            su[r0][c] = a0; su[r0+1][c] = a1; su[r0+2][c] = a2; su[r0+3][c] = a3;
        }
    }
    __syncthreads();
#pragma unroll
    for (int p = 0; p < 9; ++p) {
        int i = tid + p * 256;
        if (i < 34 * 66) {
            int r = i / 66, c = i - r * 66;
            float gys = (su[r + 2][c + 1] - su[r][c + 1]) * 0.5f;
            float gxs = (su[r + 1][c + 2] - su[r + 1][c]) * 0.5f;
            float g2 = fmaf(gxs, gxs, fmaf(gys, gys, 1e-8f));
            float ph = fminf(beta * sqrtf(xi / fmaf(eta, g2, 1e-6f)), 10.f);
            float lv = lb[refl(y0 - 1 + r, HH) * WW + refl(x0 - 1 + c, WW)];
            float fwv = fminf(fmaxf(1.f - omg * lv, 0.f), 1.f);
            pt[r][c] = ph * fwv;
        }
    }
    __syncthreads();
    const int c = tid & 63, r0 = tid >> 6;
    float mymax = 0.f;
#pragma unroll
    for (int p = 0; p < 8; ++p) {
        int r = r0 + p * 4;
        float uc = ut[r + 1][c + 1];
        float uN = ut[r][c + 1],     uS = ut[r + 2][c + 1];
        float uE = ut[r + 1][c + 2], uW = ut[r + 1][c];
        float gy = (uS - uN) * 0.5f, gx = (uE - uW) * 0.5f;
        float lap = uN + uS + uE + uW - 4.f * uc;
        float gm = sqrtf(fmaf(gx, gx, fmaf(gy, gy, 1e-8f)));
        float s = gm * fabsf(lap);
        float psi = 1e-4f * sqrtf(fmaf(nu, s * s * s, gam));
        float pN = pt[r][c + 1],     pS = pt[r + 2][c + 1];
        float pE = pt[r + 1][c + 2], pW = pt[r + 1][c];
        float dv = pN * (uN - uc) + pS * (uS - uc) + pE * (uE - uc) + pW * (uW - uc);
        int gidx = (y0 + r) * WW + x0 + c;
        float u0v = ib[gidx];
        float du = alpha * psi * dv - lam * (uc - u0v);
        float un = fminf(fmaxf(fmaf(0.1f, du, uc), 0.f), 1.f);
        db[gidx] = un;
        mymax = fmaxf(mymax, fabsf(u0v - un));
    }
    if (do_max) {
#pragma unroll
        for (int off = 32; off; off >>= 1) mymax = fmaxf(mymax, __shfl_down(mymax, off));
        if ((tid & 63) == 0) red[tid >> 6] = mymax;
        __syncthreads();
        if (tid == 0) {
            float m = fmaxf(fmaxf(red[0], red[1]), fmaxf(red[2], red[3]));
            atomicMax((unsigned int*)(Pmax + 32 * b), __float_as_uint(m));
        }
    }
}

// residual: r = |img - u| / (max + 1e-8), float4
__global__ void k_res2(const float* __restrict__ img, const float* __restrict__ u,
                       float* __restrict__ r, const float* __restrict__ Pmax)
{
    int i = blockIdx.x * 256 + threadIdx.x;   // float4 index
    int b = i >> 16;
    float inv = 1.f / (Pmax[32 * b] + 1e-8f);
    float4 a = ((const float4*)img)[i];
    float4 c = ((const float4*)u)[i];
    float4 o;
    o.x = fabsf(a.x - c.x) * inv;
    o.y = fabsf(a.y - c.y) * inv;
    o.z = fabsf(a.z - c.z) * inv;
    o.w = fabsf(a.w - c.w) * inv;
    ((float4*)r)[i] = o;
}

extern "C" void kernel_launch(void* const* d_in, const int* in_sizes, int n_in,
                              void* d_out, int out_size, void* d_ws, size_t ws_size,
                              hipStream_t stream)
{
    const float* image = (const float*)d_in[0];
    const float* lfd   = (const float*)d_in[1];

    float* out_u = (float*)d_out;
    float* out_r = out_u + NPIX;

    float* uB = (float*)d_ws;           // NPIX floats (fallback ping-pong)
    float* P  = uB + NPIX;              // params + max slots

    k_params<<<1, 64, 0, stream>>>((const float*)d_in[2], (const float*)d_in[3],
                                   (const float*)d_in[4], (const float*)d_in[5],
                                   (const float*)d_in[6], (const float*)d_in[7],
                                   (const float*)d_in[8], (const float*)d_in[9],
                                   (const float*)d_in[10], P);

    float* Pmax = P + 64;

    // saturated-phi fast path (no-op if not saturated): overlapping 56x56 output tiles
    dim3 grd2((WW + MO - 1)/MO, (HH + MO - 1)/MO, 16);
    k_mega<<<grd2, 256, 0, stream>>>(image, lfd, out_u, P, Pmax);

    // general fallback (no-op if saturated)
    dim3 grd(WW/TX, HH/TY, 16), blk(256);
    float* bufs[2] = { out_u, uB };
    for (int it = 0; it < 5; ++it) {
        const float* src = (it == 0) ? image : bufs[(it + 1) & 1];
        float* dstp = bufs[it & 1];
        k_iter<<<grd, blk, 0, stream>>>(src, image, lfd, dstp, P, Pmax, it == 4 ? 1 : 0);
    }

    k_res2<<<NPIX/1024, 256, 0, stream>>>(image, out_u, out_r, Pmax);
}

// Round 8
// 88.646 us; speedup vs baseline: 1.0824x; 1.0338x over previous
//
#include <hip/hip_runtime.h>
#include <math.h>

#define HH 512
#define WW 512
#define NPIX (16*HH*WW)
#define RAD 10
#define KS 21
#define TX 64
#define TY 32
// mega: staged 66x66 logical, LDS stride 72 (+swizzle up to col 68), output 56x56
#define MS 66
#define MSTR 72
#define MO 56

__device__ __forceinline__ int refl(int v, int n){ v = v < 0 ? -v : v; return v >= n ? 2*n - 2 - v : v; }
__device__ __forceinline__ float sigm(float x){ return 1.f/(1.f+expf(-x)); }

// P layout: [0]=alpha [1]=lam [2]=beta [3]=xi [4]=eta [5]=nu [6]=gamma [7]=omega
// [8..28]=gauss weights  [30]=saturation flag  [64+32*i]=per-image max slots
__global__ void k_params(const float* a_raw, const float* l_raw, const float* lsig,
                         const float* lbeta, const float* lxi, const float* e_raw,
                         const float* n_raw, const float* lgam, const float* o_raw,
                         float* P)
{
    if (threadIdx.x || blockIdx.x) return;
    float sigma = 0.5f + 4.5f*sigm(lsig[0]);
    float beta  = 1.f + 4.f*sigm(lbeta[0]);
    float xi    = 1.f + 4.f*sigm(lxi[0]);
    float eta   = sigm(e_raw[0]);
    P[0] = 0.6f + 1.4f*sigm(a_raw[0]);
    P[1] = 0.01f + 0.19f*sigm(l_raw[0]);
    P[2] = beta;
    P[3] = xi;
    P[4] = eta;
    P[5] = sigm(n_raw[0]);
    P[6] = 1.f + 3.f*sigm(lgam[0]);
    P[7] = sigm(o_raw[0]);
    float kk[KS], s = 0.f;
    for (int i = 0; i < KS; ++i){ float c = (float)(i-RAD); kk[i] = expf(-c*c/(2.f*sigma*sigma+1e-8f)); s += kk[i]; }
    float inv = 1.f/(s+1e-8f);
    for (int i = 0; i < KS; ++i) P[8+i] = kk[i]*inv;
    // phi saturates at 10 for ALL u in [0,1] iff beta^2*xi >= 100*(eta*g2max+1e-6), g2max=0.5.
    P[30] = (beta*beta*xi >= 100.f*(eta*0.5000002f + 1e-6f)) ? 1.f : 0.f;
    for (int i = 0; i < 16; ++i) P[64+32*i] = 0.f;
}

// Saturated-phi path: 5 iterations, u in LDS ping-pong with row-group col swizzle
// (phys col = col + ((row>>2)&3)), static 4x4 contiguous patch per thread,
// fw + u0 in registers, rolling 3-row window, fixed 64x64 compute region.
// Output inner 56x56 per tile (overlaps bitwise identical).
__global__ __launch_bounds__(256, 4)
void k_mega(const float* __restrict__ img, const float* __restrict__ lfd,
            float* __restrict__ out_u, const float* __restrict__ P, float* Pmax)
{
    if (P[30] == 0.f) return;
    __shared__ float SA[MS][MSTR];
    __shared__ float SB[MS][MSTR];
    __shared__ float red[4];
    const int tid = threadIdx.x;
    const int tx = tid & 15, ty = tid >> 4;
    const int ox = min((int)blockIdx.x * MO, WW - MO);
    const int oy = min((int)blockIdx.y * MO, HH - MO);
    const int b = blockIdx.z;
    const float* ib = img + (b<<18);
    const float* lb = lfd + (b<<18);
    float* ob = out_u + (b<<18);
    const float A = 1e-3f*P[0], lam = P[1], nu = P[5], gam = P[6], omg = P[7];
    const bool bord = (ox == 0) | (oy == 0) | (ox == WW - MO) | (oy == HH - MO);

    // stage u0 -> SA, fw -> SB (swizzled columns)
    for (int i = tid; i < MS*MS; i += 256){
        int rr = i/MS, cc = i - rr*MS;
        int gy = oy - 5 + rr, gx = ox - 5 + cc;
        if (bord){ gy = refl(gy, HH); gx = refl(gx, WW); }
        int gi = gy*WW + gx;
        int pc = cc + ((rr>>2)&3);
        SA[rr][pc] = ib[gi];
        SB[rr][pc] = fminf(fmaxf(1.f - omg*lb[gi], 0.f), 1.f);
    }
    __syncthreads();

    const int cb = 1 + 4*tx;   // first cell logical col; cell rows r0..r0+3, r0 = 1+4*ty

    // hoist fw window + u0 patch into registers (scalar reads, const offsets)
    float fNS[6][4], fW4[4], fE4[4], u0a[4][4];
#pragma unroll
    for (int jj = 0; jj < 6; ++jj){
        const int row = 4*ty + jj;                 // r0-1+jj
        const int d = (ty + (jj>>2)) & 3;
#pragma unroll
        for (int k = 0; k < 4; ++k) fNS[jj][k] = SB[row][cb + k + d];
    }
#pragma unroll
    for (int j = 0; j < 4; ++j){
        const int row = 4*ty + 1 + j;
        const int d = (ty + ((1+j)>>2)) & 3;
        fW4[j] = SB[row][cb - 1 + d];
        fE4[j] = SB[row][cb + 4 + d];
#pragma unroll
        for (int k = 0; k < 4; ++k) u0a[j][k] = SA[row][cb + k + d];
    }
    __syncthreads();   // all SB (fw) reads done before iter1 overwrites SB

    float mymax = 0.f;
    const bool inner = (tx >= 1) & (tx <= 14) & (ty >= 1) & (ty <= 14);
    float* obase0 = ob + (oy - 4 + 4*ty)*WW + (ox - 4 + 4*tx);

#define STEP(SRC, DST, LAST) { \
    float c0[4], c1[4], c2[4]; \
    { const int row = 4*ty; const int d = ty & 3; \
      _Pragma("unroll") for (int k = 0; k < 4; ++k) c0[k] = SRC[row][cb+k+d]; } \
    { const int row = 4*ty + 1; const int d = ty & 3; \
      _Pragma("unroll") for (int k = 0; k < 4; ++k) c1[k] = SRC[row][cb+k+d]; } \
    _Pragma("unroll") \
    for (int j = 0; j < 4; ++j){ \
        const int rowS = 4*ty + 2 + j; const int dS = (ty + ((2+j)>>2)) & 3; \
        const int rowC = 4*ty + 1 + j; const int dC = (ty + ((1+j)>>2)) & 3; \
        _Pragma("unroll") for (int k = 0; k < 4; ++k) c2[k] = SRC[rowS][cb+k+dS]; \
        float uwv = SRC[rowC][cb - 1 + dC]; \
        float uev = SRC[rowC][cb + 4 + dC]; \
        float un0, un1, un2, un3; \
        _Pragma("unroll") for (int k = 0; k < 4; ++k){ \
            float uc = c1[k]; \
            float uN = c0[k], uS = c2[k]; \
            float uW = k ? c1[k-1] : uwv; \
            float uE = (k < 3) ? c1[k+1] : uev; \
            float fN = fNS[j][k], fS = fNS[j+2][k]; \
            float fWv = k ? fNS[j+1][k-1] : fW4[j]; \
            float fEv = (k < 3) ? fNS[j+1][k+1] : fE4[j]; \
            float gyv = (uS-uN)*0.5f, gxv = (uE-uW)*0.5f; \
            float lap = (uN+uS)+(uE+uW) - 4.f*uc; \
            float gm = sqrtf(fmaf(gxv,gxv, fmaf(gyv,gyv, 1e-8f))); \
            float s = gm*fabsf(lap); \
            float psi = sqrtf(fmaf(nu, s*s*s, gam)); \
            float dv = fN*(uN-uc) + fS*(uS-uc) + fEv*(uE-uc) + fWv*(uW-uc); \
            float du = fmaf(A*psi, dv, -lam*(uc - u0a[j][k])); \
            float unk = fminf(fmaxf(fmaf(0.1f, du, uc), 0.f), 1.f); \
            if (k == 0) un0 = unk; else if (k == 1) un1 = unk; \
            else if (k == 2) un2 = unk; else un3 = unk; \
        } \
        if (LAST){ \
            if (inner){ \
                float4 o; o.x = un0; o.y = un1; o.z = un2; o.w = un3; \
                *(float4*)(obase0 + j*WW) = o; \
                mymax = fmaxf(mymax, fabsf(u0a[j][0] - un0)); \
                mymax = fmaxf(mymax, fabsf(u0a[j][1] - un1)); \
                mymax = fmaxf(mymax, fabsf(u0a[j][2] - un2)); \
                mymax = fmaxf(mymax, fabsf(u0a[j][3] - un3)); \
            } \
        } else { \
            DST[rowC][cb + 0 + dC] = un0; \
            DST[rowC][cb + 1 + dC] = un1; \
            DST[rowC][cb + 2 + dC] = un2; \
            DST[rowC][cb + 3 + dC] = un3; \
        } \
        _Pragma("unroll") for (int k = 0; k < 4; ++k){ c0[k] = c1[k]; c1[k] = c2[k]; } \
    } \
    if (!LAST) __syncthreads(); }

    STEP(SA, SB, 0)
    STEP(SB, SA, 0)
    STEP(SA, SB, 0)
    STEP(SB, SA, 0)
    STEP(SA, SB, 1)
#undef STEP

#pragma unroll
    for (int off = 32; off; off >>= 1) mymax = fmaxf(mymax, __shfl_down(mymax, off));
    if ((tid & 63) == 0) red[tid >> 6] = mymax;
    __syncthreads();
    if (tid == 0){
        float m = fmaxf(fmaxf(red[0], red[1]), fmaxf(red[2], red[3]));
        atomicMax((unsigned int*)(Pmax + 32*b), __float_as_uint(m));
    }
}

// General-path fallback (fully-fused single iteration). Early-exits when saturated.
__global__ __launch_bounds__(256)
void k_iter(const float* __restrict__ src, const float* __restrict__ img,
            const float* __restrict__ lfd, float* __restrict__ dst,
            const float* __restrict__ P, float* Pmax, int do_max)
{
    if (P[30] != 0.f) return;
    __shared__ __attribute__((aligned(16))) float sh[56][72];
    __shared__ float su[36][72];
    __shared__ float ut[34][72];
    __shared__ float red[4];
    float (*pt)[72] = sh;

    const int tid = threadIdx.x;
    const int x0 = blockIdx.x * TX;
    const int y0 = blockIdx.y * TY;
    const int b  = blockIdx.z;
    const float* sb = src + (b << 18);
    const float* ib = img + (b << 18);
    const float* lb = lfd + (b << 18);
    float* db = dst + (b << 18);

    float kw[KS];
#pragma unroll
    for (int j = 0; j < KS; ++j) kw[j] = P[8 + j];
    const float alpha = P[0], lam = P[1], beta = P[2], xi = P[3];
    const float eta = P[4], nu = P[5], gam = P[6], omg = P[7];

#pragma unroll
    for (int p = 0; p < 9; ++p) {
        int i = tid + p * 256;
        if (i < 34 * 66) {
            int r = i / 66, c = i - r * 66;
            ut[r][c] = sb[refl(y0 - 1 + r, HH) * WW + refl(x0 - 1 + c, WW)];
        }
    }
#pragma unroll
    for (int p = 0; p < 4; ++p) {
        int i = tid + p * 256;
        if (i < 56 * 17) {
            int hr = i / 17, g = i - hr * 17;
            const float* row = sb + refl(y0 - 12 + hr, HH) * WW;
            int gxs = x0 - 12 + 4 * g;
            float wv[24];
            if (gxs >= 0 && gxs + 23 < WW) {
                const float4* p4 = (const float4*)(row + gxs);
#pragma unroll
                for (int q = 0; q < 6; ++q) {
                    float4 v = p4[q];
                    wv[4*q] = v.x; wv[4*q+1] = v.y; wv[4*q+2] = v.z; wv[4*q+3] = v.w;
                }
            } else {
#pragma unroll
                for (int q = 0; q < 24; ++q) wv[q] = row[refl(gxs + q, WW)];
            }
            float a0 = 0.f, a1 = 0.f, a2 = 0.f, a3 = 0.f;
#pragma unroll
            for (int j = 0; j < KS; ++j) {
                a0 = fmaf(kw[j], wv[j],     a0);
                a1 = fmaf(kw[j], wv[j + 1], a1);
                a2 = fmaf(kw[j], wv[j + 2], a2);
                a3 = fmaf(kw[j], wv[j + 3], a3);
            }
            float4 o; o.x = a0; o.y = a1; o.z = a2; o.w = a3;
            *(float4*)&sh[hr][4 * g] = o;
        }
    }
    __syncthreads();
#pragma unroll
    for (int p = 0; p < 3; ++p) {
        int i = tid + p * 256;
        if (i < 9 * 68) {
            int rg = i / 68, c = i - rg * 68;
            int r0 = rg * 4;
            float a0 = 0.f, a1 = 0.f, a2 = 0.f, a3 = 0.f;
#pragma unroll
            for (int q = 0; q < 24; ++q) {
                float s = sh[r0 + q][c];
                if (q <= 20)           a0 = fmaf(kw[q],     s, a0);
                if (q >= 1 && q <= 21) a1 = fmaf(kw[q - 1], s, a1);
                if (q >= 2 && q <= 22) a2 = fmaf(kw[q - 2], s, a2);
                if (q >= 3)            a3 = fmaf(kw[q - 3], s, a3);
            }
            su[r0][c] = a0; su[r0+1][c] = a1; su[r0+2][c] = a2; su[r0+3][c] = a3;
        }
    }
    __syncthreads();
#pragma unroll
    for (int p = 0; p < 9; ++p) {
        int i = tid + p * 256;
        if (i < 34 * 66) {
            int r = i / 66, c = i - r * 66;
            float gys = (su[r + 2][c + 1] - su[r][c + 1]) * 0.5f;
            float gxs = (su[r + 1][c + 2] - su[r + 1][c]) * 0.5f;
            float g2 = fmaf(gxs, gxs, fmaf(gys, gys, 1e-8f));
            float ph = fminf(beta * sqrtf(xi / fmaf(eta, g2, 1e-6f)), 10.f);
            float lv = lb[refl(y0 - 1 + r, HH) * WW + refl(x0 - 1 + c, WW)];
            float fwv = fminf(fmaxf(1.f - omg * lv, 0.f), 1.f);
            pt[r][c] = ph * fwv;
        }
    }
    __syncthreads();
    const int c = tid & 63, r0 = tid >> 6;
    float mymax = 0.f;
#pragma unroll
    for (int p = 0; p < 8; ++p) {
        int r = r0 + p * 4;
        float uc = ut[r + 1][c + 1];
        float uN = ut[r][c + 1],     uS = ut[r + 2][c + 1];
        float uE = ut[r + 1][c + 2], uW = ut[r + 1][c];
        float gy = (uS - uN) * 0.5f, gx = (uE - uW) * 0.5f;
        float lap = uN + uS + uE + uW - 4.f * uc;
        float gm = sqrtf(fmaf(gx, gx, fmaf(gy, gy, 1e-8f)));
        float s = gm * fabsf(lap);
        float psi = 1e-4f * sqrtf(fmaf(nu, s * s * s, gam));
        float pN = pt[r][c + 1],     pS = pt[r + 2][c + 1];
        float pE = pt[r + 1][c + 2], pW = pt[r + 1][c];
        float dv = pN * (uN - uc) + pS * (uS - uc) + pE * (uE - uc) + pW * (uW - uc);
        int gidx = (y0 + r) * WW + x0 + c;
        float u0v = ib[gidx];
        float du = alpha * psi * dv - lam * (uc - u0v);
        float un = fminf(fmaxf(fmaf(0.1f, du, uc), 0.f), 1.f);
        db[gidx] = un;
        mymax = fmaxf(mymax, fabsf(u0v - un));
    }
    if (do_max) {
#pragma unroll
        for (int off = 32; off; off >>= 1) mymax = fmaxf(mymax, __shfl_down(mymax, off));
        if ((tid & 63) == 0) red[tid >> 6] = mymax;
        __syncthreads();
        if (tid == 0) {
            float m = fmaxf(fmaxf(red[0], red[1]), fmaxf(red[2], red[3]));
            atomicMax((unsigned int*)(Pmax + 32 * b), __float_as_uint(m));
        }
    }
}

// residual: r = |img - u| / (max + 1e-8), float4
__global__ void k_res2(const float* __restrict__ img, const float* __restrict__ u,
                       float* __restrict__ r, const float* __restrict__ Pmax)
{
    int i = blockIdx.x * 256 + threadIdx.x;   // float4 index
    int b = i >> 16;
    float inv = 1.f / (Pmax[32 * b] + 1e-8f);
    float4 a = ((const float4*)img)[i];
    float4 c = ((const float4*)u)[i];
    float4 o;
    o.x = fabsf(a.x - c.x) * inv;
    o.y = fabsf(a.y - c.y) * inv;
    o.z = fabsf(a.z - c.z) * inv;
    o.w = fabsf(a.w - c.w) * inv;
    ((float4*)r)[i] = o;
}

extern "C" void kernel_launch(void* const* d_in, const int* in_sizes, int n_in,
                              void* d_out, int out_size, void* d_ws, size_t ws_size,
                              hipStream_t stream)
{
    const float* image = (const float*)d_in[0];
    const float* lfd   = (const float*)d_in[1];

    float* out_u = (float*)d_out;
    float* out_r = out_u + NPIX;

    float* uB = (float*)d_ws;           // NPIX floats (fallback ping-pong)
    float* P  = uB + NPIX;              // params + max slots

    k_params<<<1, 64, 0, stream>>>((const float*)d_in[2], (const float*)d_in[3],
                                   (const float*)d_in[4], (const float*)d_in[5],
                                   (const float*)d_in[6], (const float*)d_in[7],
                                   (const float*)d_in[8], (const float*)d_in[9],
                                   (const float*)d_in[10], P);

    float* Pmax = P + 64;

    // saturated-phi fast path (no-op if not saturated): overlapping 56x56 output tiles
    dim3 grd2((WW + MO - 1)/MO, (HH + MO - 1)/MO, 16);
    k_mega<<<grd2, 256, 0, stream>>>(image, lfd, out_u, P, Pmax);

    // general fallback (no-op if saturated)
    dim3 grd(WW/TX, HH/TY, 16), blk(256);
    float* bufs[2] = { out_u, uB };
    for (int it = 0; it < 5; ++it) {
        const float* src = (it == 0) ? image : bufs[(it + 1) & 1];
        float* dstp = bufs[it & 1];
        k_iter<<<grd, blk, 0, stream>>>(src, image, lfd, dstp, P, Pmax, it == 4 ? 1 : 0);
    }

    k_res2<<<NPIX/1024, 256, 0, stream>>>(image, out_u, out_r, Pmax);
}

// Round 9
// 79.781 us; speedup vs baseline: 1.2027x; 1.1111x over previous
//
#include <hip/hip_runtime.h>
#include <math.h>

#define HH 512
#define WW 512
#define NPIX (16*HH*WW)
#define RAD 10
#define KS 21
#define TX 64
#define TY 32
// mega tile: output 64x32, staged 74x42, LDS stride 75 (odd -> ~2-way banks)
#define SH 42
#define SW 74
#define SSTR 75

__device__ __forceinline__ int refl(int v, int n){ v = v < 0 ? -v : v; return v >= n ? 2*n - 2 - v : v; }
__device__ __forceinline__ float sigm(float x){ return 1.f/(1.f+expf(-x)); }

// P layout: [0]=alpha [1]=lam [2]=beta [3]=xi [4]=eta [5]=nu [6]=gamma [7]=omega
// [8..28]=gauss weights  [30]=saturation flag  [64+32*i]=per-image max slots
__global__ void k_params(const float* a_raw, const float* l_raw, const float* lsig,
                         const float* lbeta, const float* lxi, const float* e_raw,
                         const float* n_raw, const float* lgam, const float* o_raw,
                         float* P)
{
    if (threadIdx.x || blockIdx.x) return;
    float sigma = 0.5f + 4.5f*sigm(lsig[0]);
    float beta  = 1.f + 4.f*sigm(lbeta[0]);
    float xi    = 1.f + 4.f*sigm(lxi[0]);
    float eta   = sigm(e_raw[0]);
    P[0] = 0.6f + 1.4f*sigm(a_raw[0]);
    P[1] = 0.01f + 0.19f*sigm(l_raw[0]);
    P[2] = beta;
    P[3] = xi;
    P[4] = eta;
    P[5] = sigm(n_raw[0]);
    P[6] = 1.f + 3.f*sigm(lgam[0]);
    P[7] = sigm(o_raw[0]);
    float kk[KS], s = 0.f;
    for (int i = 0; i < KS; ++i){ float c = (float)(i-RAD); kk[i] = expf(-c*c/(2.f*sigma*sigma+1e-8f)); s += kk[i]; }
    float inv = 1.f/(s+1e-8f);
    for (int i = 0; i < KS; ++i) P[8+i] = kk[i]*inv;
    // phi saturates at 10 for ALL u in [0,1] iff beta^2*xi >= 100*(eta*g2max+1e-6), g2max=0.5.
    P[30] = (beta*beta*xi >= 100.f*(eta*0.5000002f + 1e-6f)) ? 1.f : 0.f;
    for (int i = 0; i < 16; ++i) P[64+32*i] = 0.f;
}

#define ROW6(v, S, off) float v##0=(S)[(off)], v##1=(S)[(off)+1], v##2=(S)[(off)+2], \
                              v##3=(S)[(off)+3], v##4=(S)[(off)+4], v##5=(S)[(off)+5];
#define ROW8(v, S, off) float v##m=(S)[(off)-1], v##0=(S)[(off)], v##1=(S)[(off)+1], v##2=(S)[(off)+2], \
                              v##3=(S)[(off)+3], v##4=(S)[(off)+4], v##5=(S)[(off)+5], v##6=(S)[(off)+6];

// Saturated-phi path: 5 iterations in LDS ping-pong (odd stride), static 6x2 patch
// per thread, fw-edges + u0 in NAMED scalar registers, fixed 72x40 compute region.
// Final iter writes u + raw residual for the 64x32 core.
__global__ __launch_bounds__(256, 4)
void k_mega(const float* __restrict__ img, const float* __restrict__ lfd,
            float* __restrict__ out_u, float* __restrict__ out_r,
            const float* __restrict__ P, float* Pmax)
{
    if (P[30] == 0.f) return;
    __shared__ float SA[SH*SSTR];
    __shared__ float SB[SH*SSTR];
    __shared__ float red[4];
    const int tid = threadIdx.x;
    const bool active = tid < 240;
    const int pid = active ? tid : 0;
    const int py = pid / 12;            // 0..19
    const int px = pid - 12*py;         // 0..11
    const int ox = blockIdx.x * TX, oy = blockIdx.y * TY;
    const int b = blockIdx.z;
    const float* ib = img + (b<<18);
    const float* lb = lfd + (b<<18);
    const float A = 1e-3f*P[0], lam = P[1], nu = P[5], gam = P[6], omg = P[7];
    const bool bord = (ox == 0) | (oy == 0) | (ox == WW - TX) | (oy == HH - TY);

    // stage u0 -> SA, fw -> SB
    for (int i = tid; i < SW*SH; i += 256){
        int r = i / SW, c = i - r*SW;
        int gy = oy - 5 + r, gx = ox - 5 + c;
        if (bord){ gy = refl(gy, HH); gx = refl(gx, WW); }
        int gi = gy*WW + gx;
        SA[r*SSTR + c] = ib[gi];
        SB[r*SSTR + c] = fminf(fmaxf(1.f - omg*lb[gi], 0.f), 1.f);
    }
    __syncthreads();

    const int c0 = 1 + 6*px;            // 1..67
    const int r0 = 1 + 2*py;            // 1..39 (rows r0, r0+1)
    const int bi = r0*SSTR + c0;

    // hoist fw window + u0 into named scalars
    ROW6(fa, SB, bi-SSTR) ROW8(fb, SB, bi) ROW8(fc, SB, bi+SSTR) ROW6(fd, SB, bi+2*SSTR)
    float zb0=SA[bi],   zb1=SA[bi+1],   zb2=SA[bi+2],   zb3=SA[bi+3],   zb4=SA[bi+4],   zb5=SA[bi+5];
    float zc0=SA[bi+SSTR], zc1=SA[bi+SSTR+1], zc2=SA[bi+SSTR+2], zc3=SA[bi+SSTR+3], zc4=SA[bi+SSTR+4], zc5=SA[bi+SSTR+5];
    __syncthreads();    // all fw reads done before iter1 overwrites SB

    auto CF = [&](float cc, float cn, float cs, float cw, float ce,
                  float fn, float fs, float fww, float fe, float z) -> float {
        float gyv = (cs - cn)*0.5f, gxv = (ce - cw)*0.5f;
        float lap = (cn + cs) + (ce + cw) - 4.f*cc;
        float gm = sqrtf(fmaf(gxv, gxv, fmaf(gyv, gyv, 1e-8f)));
        float s = gm*fabsf(lap);
        float psi = sqrtf(fmaf(nu, s*s*s, gam));
        float dv = fn*(cn-cc) + fs*(cs-cc) + fe*(ce-cc) + fww*(cw-cc);
        float du = fmaf(A*psi, dv, -lam*(cc - z));
        return fminf(fmaxf(fmaf(0.1f, du, cc), 0.f), 1.f);
    };

#define CELLS \
    float nb0 = CF(ub0, ua0, uc0, ubm, ub1, fa0, fc0, fbm, fb1, zb0); \
    float nb1 = CF(ub1, ua1, uc1, ub0, ub2, fa1, fc1, fb0, fb2, zb1); \
    float nb2 = CF(ub2, ua2, uc2, ub1, ub3, fa2, fc2, fb1, fb3, zb2); \
    float nb3 = CF(ub3, ua3, uc3, ub2, ub4, fa3, fc3, fb2, fb4, zb3); \
    float nb4 = CF(ub4, ua4, uc4, ub3, ub5, fa4, fc4, fb3, fb5, zb4); \
    float nb5 = CF(ub5, ua5, uc5, ub4, ub6, fa5, fc5, fb4, fb6, zb5); \
    float nc0 = CF(uc0, ub0, ud0, ucm, uc1, fb0, fd0, fcm, fc1, zc0); \
    float nc1 = CF(uc1, ub1, ud1, uc0, uc2, fb1, fd1, fc0, fc2, zc1); \
    float nc2 = CF(uc2, ub2, ud2, uc1, uc3, fb2, fd2, fc1, fc3, zc2); \
    float nc3 = CF(uc3, ub3, ud3, uc2, uc4, fb3, fd3, fc2, fc4, zc3); \
    float nc4 = CF(uc4, ub4, ud4, uc3, uc5, fb4, fd4, fc3, fc5, zc4); \
    float nc5 = CF(uc5, ub5, ud5, uc4, uc6, fb5, fd5, fc4, fc6, zc5);

#define STEP(S, D) { \
    ROW6(ua, S, bi-SSTR) ROW8(ub, S, bi) ROW8(uc, S, bi+SSTR) ROW6(ud, S, bi+2*SSTR) \
    CELLS \
    if (active){ \
        D[bi]   = nb0; D[bi+1] = nb1; D[bi+2] = nb2; D[bi+3] = nb3; D[bi+4] = nb4; D[bi+5] = nb5; \
        D[bi+SSTR]   = nc0; D[bi+SSTR+1] = nc1; D[bi+SSTR+2] = nc2; \
        D[bi+SSTR+3] = nc3; D[bi+SSTR+4] = nc4; D[bi+SSTR+5] = nc5; \
    } \
    } __syncthreads();

    STEP(SA, SB)
    STEP(SB, SA)
    STEP(SA, SB)
    STEP(SB, SA)

    // final iteration: compute and store core (rows 5..36, cols 5..68) to global
    float mymax = 0.f;
    {
        ROW6(ua, SA, bi-SSTR) ROW8(ub, SA, bi) ROW8(uc, SA, bi+SSTR) ROW6(ud, SA, bi+2*SSTR)
        CELLS
        if (active && py >= 2 && py <= 17){
            float* ou = out_u + (b<<18) + (oy + r0 - 5)*WW + (ox + c0 - 5);
            float* orr = out_r + (b<<18) + (oy + r0 - 5)*WW + (ox + c0 - 5);
#define EMIT(K, NB, NC, ZB, ZC) \
            if (c0 + K >= 5 && c0 + K <= 68){ \
                ou[K] = NB; ou[WW + K] = NC; \
                float vb = fabsf(ZB - NB), vc = fabsf(ZC - NC); \
                orr[K] = vb; orr[WW + K] = vc; \
                mymax = fmaxf(mymax, fmaxf(vb, vc)); \
            }
            EMIT(0, nb0, nc0, zb0, zc0)
            EMIT(1, nb1, nc1, zb1, zc1)
            EMIT(2, nb2, nc2, zb2, zc2)
            EMIT(3, nb3, nc3, zb3, zc3)
            EMIT(4, nb4, nc4, zb4, zc4)
            EMIT(5, nb5, nc5, zb5, zc5)
#undef EMIT
        }
    }
#undef STEP
#undef CELLS

#pragma unroll
    for (int off = 32; off; off >>= 1) mymax = fmaxf(mymax, __shfl_down(mymax, off));
    if ((tid & 63) == 0) red[tid >> 6] = mymax;
    __syncthreads();
    if (tid == 0){
        float m = fmaxf(fmaxf(red[0], red[1]), fmaxf(red[2], red[3]));
        atomicMax((unsigned int*)(Pmax + 32*b), __float_as_uint(m));
    }
}

// General-path fallback (fully-fused single iteration). Early-exits when saturated.
__global__ __launch_bounds__(256)
void k_iter(const float* __restrict__ src, const float* __restrict__ img,
            const float* __restrict__ lfd, float* __restrict__ dst,
            float* __restrict__ resid,
            const float* __restrict__ P, float* Pmax, int do_max)
{
    if (P[30] != 0.f) return;
    __shared__ __attribute__((aligned(16))) float sh[56][72];
    __shared__ float su[36][72];
    __shared__ float ut[34][72];
    __shared__ float red[4];
    float (*pt)[72] = sh;

    const int tid = threadIdx.x;
    const int x0 = blockIdx.x * TX;
    const int y0 = blockIdx.y * TY;
    const int b  = blockIdx.z;
    const float* sb = src + (b << 18);
    const float* ib = img + (b << 18);
    const float* lb = lfd + (b << 18);
    float* db = dst + (b << 18);

    float kw[KS];
#pragma unroll
    for (int j = 0; j < KS; ++j) kw[j] = P[8 + j];
    const float alpha = P[0], lam = P[1], beta = P[2], xi = P[3];
    const float eta = P[4], nu = P[5], gam = P[6], omg = P[7];

#pragma unroll
    for (int p = 0; p < 9; ++p) {
        int i = tid + p * 256;
        if (i < 34 * 66) {
            int r = i / 66, c = i - r * 66;
            ut[r][c] = sb[refl(y0 - 1 + r, HH) * WW + refl(x0 - 1 + c, WW)];
        }
    }
#pragma unroll
    for (int p = 0; p < 4; ++p) {
        int i = tid + p * 256;
        if (i < 56 * 17) {
            int hr = i / 17, g = i - hr * 17;
            const float* row = sb + refl(y0 - 12 + hr, HH) * WW;
            int gxs = x0 - 12 + 4 * g;
            float wv[24];
            if (gxs >= 0 && gxs + 23 < WW) {
                const float4* p4 = (const float4*)(row + gxs);
#pragma unroll
                for (int q = 0; q < 6; ++q) {
                    float4 v = p4[q];
                    wv[4*q] = v.x; wv[4*q+1] = v.y; wv[4*q+2] = v.z; wv[4*q+3] = v.w;
                }
            } else {
#pragma unroll
                for (int q = 0; q < 24; ++q) wv[q] = row[refl(gxs + q, WW)];
            }
            float a0 = 0.f, a1 = 0.f, a2 = 0.f, a3 = 0.f;
#pragma unroll
            for (int j = 0; j < KS; ++j) {
                a0 = fmaf(kw[j], wv[j],     a0);
                a1 = fmaf(kw[j], wv[j + 1], a1);
                a2 = fmaf(kw[j], wv[j + 2], a2);
                a3 = fmaf(kw[j], wv[j + 3], a3);
            }
            float4 o; o.x = a0; o.y = a1; o.z = a2; o.w = a3;
            *(float4*)&sh[hr][4 * g] = o;
        }
    }
    __syncthreads();
#pragma unroll
    for (int p = 0; p < 3; ++p) {
        int i = tid + p * 256;
        if (i < 9 * 68) {
            int rg = i / 68, c = i - rg * 68;
            int r0 = rg * 4;
            float a0 = 0.f, a1 = 0.f, a2 = 0.f, a3 = 0.f;
#pragma unroll
            for (int q = 0; q < 24; ++q) {
                float s = sh[r0 + q][c];
                if (q <= 20)           a0 = fmaf(kw[q],     s, a0);
                if (q >= 1 && q <= 21) a1 = fmaf(kw[q - 1], s, a1);
                if (q >= 2 && q <= 22) a2 = fmaf(kw[q - 2], s, a2);
                if (q >= 3)            a3 = fmaf(kw[q - 3], s, a3);
            }
            su[r0][c] = a0; su[r0+1][c] = a1; su[r0+2][c] = a2; su[r0+3][c] = a3;
        }
    }
    __syncthreads();
#pragma unroll
    for (int p = 0; p < 9; ++p) {
        int i = tid + p * 256;
        if (i < 34 * 66) {
            int r = i / 66, c = i - r * 66;
            float gys = (su[r + 2][c + 1] - su[r][c + 1]) * 0.5f;
            float gxs = (su[r + 1][c + 2] - su[r + 1][c]) * 0.5f;
            float g2 = fmaf(gxs, gxs, fmaf(gys, gys, 1e-8f));
            float ph = fminf(beta * sqrtf(xi / fmaf(eta, g2, 1e-6f)), 10.f);
            float lv = lb[refl(y0 - 1 + r, HH) * WW + refl(x0 - 1 + c, WW)];
            float fwv = fminf(fmaxf(1.f - omg * lv, 0.f), 1.f);
            pt[r][c] = ph * fwv;
        }
    }
    __syncthreads();
    const int c = tid & 63, r0 = tid >> 6;
    float mymax = 0.f;
#pragma unroll
    for (int p = 0; p < 8; ++p) {
        int r = r0 + p * 4;
        float uc = ut[r + 1][c + 1];
        float uN = ut[r][c + 1],     uS = ut[r + 2][c + 1];
        float uE = ut[r + 1][c + 2], uW = ut[r + 1][c];
        float gy = (uS - uN) * 0.5f, gx = (uE - uW) * 0.5f;
        float lap = uN + uS + uE + uW - 4.f * uc;
        float gm = sqrtf(fmaf(gx, gx, fmaf(gy, gy, 1e-8f)));
        float s = gm * fabsf(lap);
        float psi = 1e-4f * sqrtf(fmaf(nu, s * s * s, gam));
        float pN = pt[r][c + 1],     pS = pt[r + 2][c + 1];
        float pE = pt[r + 1][c + 2], pW = pt[r + 1][c];
        float dv = pN * (uN - uc) + pS * (uS - uc) + pE * (uE - uc) + pW * (uW - uc);
        int gidx = (y0 + r) * WW + x0 + c;
        float u0v = ib[gidx];
        float du = alpha * psi * dv - lam * (uc - u0v);
        float un = fminf(fmaxf(fmaf(0.1f, du, uc), 0.f), 1.f);
        db[gidx] = un;
        if (do_max){
            float v = fabsf(u0v - un);
            resid[(b<<18) + gidx] = v;
            mymax = fmaxf(mymax, v);
        }
    }
    if (do_max) {
#pragma unroll
        for (int off = 32; off; off >>= 1) mymax = fmaxf(mymax, __shfl_down(mymax, off));
        if ((tid & 63) == 0) red[tid >> 6] = mymax;
        __syncthreads();
        if (tid == 0) {
            float m = fmaxf(fmaxf(red[0], red[1]), fmaxf(red[2], red[3]));
            atomicMax((unsigned int*)(Pmax + 32 * b), __float_as_uint(m));
        }
    }
}

// in-place normalize of residual
__global__ void k_res2(float* __restrict__ r, const float* __restrict__ Pmax)
{
    int i = blockIdx.x * 256 + threadIdx.x;   // float4 index
    int b = i >> 16;
    float inv = 1.f / (Pmax[32 * b] + 1e-8f);
    float4 v = ((const float4*)r)[i];
    v.x *= inv; v.y *= inv; v.z *= inv; v.w *= inv;
    ((float4*)r)[i] = v;
}

extern "C" void kernel_launch(void* const* d_in, const int* in_sizes, int n_in,
                              void* d_out, int out_size, void* d_ws, size_t ws_size,
                              hipStream_t stream)
{
    const float* image = (const float*)d_in[0];
    const float* lfd   = (const float*)d_in[1];

    float* out_u = (float*)d_out;
    float* out_r = out_u + NPIX;

    float* uB = (float*)d_ws;           // NPIX floats (fallback ping-pong)
    float* P  = uB + NPIX;              // params + max slots

    k_params<<<1, 64, 0, stream>>>((const float*)d_in[2], (const float*)d_in[3],
                                   (const float*)d_in[4], (const float*)d_in[5],
                                   (const float*)d_in[6], (const float*)d_in[7],
                                   (const float*)d_in[8], (const float*)d_in[9],
                                   (const float*)d_in[10], P);

    float* Pmax = P + 64;

    // saturated-phi fast path (no-op if not saturated)
    dim3 grd(WW/TX, HH/TY, 16), blk(256);
    k_mega<<<grd, blk, 0, stream>>>(image, lfd, out_u, out_r, P, Pmax);

    // general fallback (no-op if saturated)
    float* bufs[2] = { out_u, uB };
    for (int it = 0; it < 5; ++it) {
        const float* src = (it == 0) ? image : bufs[(it + 1) & 1];
        float* dstp = bufs[it & 1];
        k_iter<<<grd, blk, 0, stream>>>(src, image, lfd, dstp, out_r, P, Pmax, it == 4 ? 1 : 0);
    }

    k_res2<<<NPIX/1024, 256, 0, stream>>>(out_r, Pmax);
}